// Round 3
// baseline (208.177 us; speedup 1.0000x reference)
//
#include <hip/hip_runtime.h>
#include <hip/hip_cooperative_groups.h>
#include <cstdint>

namespace cg = cooperative_groups;

namespace {
constexpr int T = 1024;
constexpr int B = 8;
constexpr int D = 512;
constexpr int W = 32;
constexpr int M = T * B; // 8192 rows (t*B+b)
}

using half8  = __attribute__((ext_vector_type(8))) _Float16;
using f32x16 = __attribute__((ext_vector_type(16))) float;

__device__ __forceinline__ void gload16(const void* g, void* l) {
    __builtin_amdgcn_global_load_lds(
        (const __attribute__((address_space(1))) void*)g,
        (__attribute__((address_space(3))) void*)l, 16, 0, 0);
}

__device__ __forceinline__ float fast_tanh(float x) {
    float e = __expf(2.f * x);
    return 1.f - 2.f / (e + 1.f);
}

// ---------- phase 0: X fp32 -> Ah fp16 [M][D]; W fp32 [e][d] -> Bt fp16 [d][e]
__device__ __forceinline__ void phase_prep(int bid, int tid,
                                           const float* __restrict__ X,
                                           const float* __restrict__ Wm,
                                           _Float16* __restrict__ Ah,
                                           _Float16* __restrict__ Bt)
{
    const int g = bid * 256 + tid;            // 0..65535
    const float4* X4 = reinterpret_cast<const float4*>(X);
#pragma unroll
    for (int k = 0; k < 8; ++k) {
        const int c = g + k * 65536;          // half8 chunk 0..524287
        const float4 v0 = X4[(size_t)c * 2];
        const float4 v1 = X4[(size_t)c * 2 + 1];
        half8 h;
        h[0] = (_Float16)v0.x; h[1] = (_Float16)v0.y; h[2] = (_Float16)v0.z; h[3] = (_Float16)v0.w;
        h[4] = (_Float16)v1.x; h[5] = (_Float16)v1.y; h[6] = (_Float16)v1.z; h[7] = (_Float16)v1.w;
        *reinterpret_cast<half8*>(Ah + (size_t)c * 8) = h;
    }
    if (g < 32768) {                          // 512 d x 64 e-groups
        const int d  = g & 511;
        const int eg = g >> 9;
        half8 h;
#pragma unroll
        for (int j = 0; j < 8; ++j)
            h[j] = (_Float16)Wm[(size_t)(eg * 8 + j) * 512 + d]; // coalesced over d
        *reinterpret_cast<half8*>(Bt + (size_t)d * 512 + eg * 8) = h;
    }
}

// ---------- phase 1: fused GEMM + tanh + proj-dot -> spart[8][M] (64-col partials)
__device__ __forceinline__ void phase_gemm(int bid, int tid,
                                           const _Float16* __restrict__ Ah,
                                           const _Float16* __restrict__ Bt,
                                           const float* __restrict__ proj,
                                           float* __restrict__ spart)
{
    __shared__ char lds_buf[65536]; // [2 bufs][A 16K | B 16K]

    const int lane = tid & 63;
    const int wv   = tid >> 6;
    const int wm   = wv >> 1;
    const int wn   = wv & 1;
    const int hi   = lane >> 5;
    const int l31  = lane & 31;
    const int l7   = lane & 7;

    const int wgid = (bid & 7) * 32 + (bid >> 3); // XCD-aware swizzle
    const int mb   = wgid >> 2;
    const int nb   = wgid & 3;
    const int m0   = mb * 128;
    const int n0   = nb * 128;

    const int wbase = __builtin_amdgcn_readfirstlane(tid & ~63);

    f32x16 acc00 = {}, acc01 = {}, acc10 = {}, acc11 = {};

    auto stage = [&](int bufi, int kt) {
        char* abase = lds_buf + bufi * 32768;
        char* bbase = abase + 16384;
        const int kbase = kt * 64;
#pragma unroll
        for (int i = 0; i < 4; ++i) {
            const int c   = i * 256 + tid;
            const int row = c >> 3;
            const int ch  = c & 7;
            const int koff = kbase + ((ch ^ (row & 7)) << 3);
            gload16(Ah + (size_t)(m0 + row) * 512 + koff,
                    abase + (size_t)(i * 256 + wbase) * 16);
            gload16(Bt + (size_t)(n0 + row) * 512 + koff,
                    bbase + (size_t)(i * 256 + wbase) * 16);
        }
    };

    stage(0, 0);
    asm volatile("s_waitcnt vmcnt(0)" ::: "memory");
    __syncthreads();

    int cur = 0;
    const int rowA0 = wm * 64 + l31;
    const int rowA1 = rowA0 + 32;
    const int colB0 = wn * 64 + l31;
    const int colB1 = colB0 + 32;

    for (int kt = 0; kt < 8; ++kt) {
        if (kt < 7) stage(cur ^ 1, kt + 1);

        const char* Ab = lds_buf + cur * 32768;
        const char* Bb = Ab + 16384;

        half8 af0[4], af1[4], bf0[4], bf1[4];
#pragma unroll
        for (int s = 0; s < 4; ++s) {
            const int ch = ((2 * s + hi) ^ l7) << 4;
            af0[s] = *reinterpret_cast<const half8*>(Ab + rowA0 * 128 + ch);
            af1[s] = *reinterpret_cast<const half8*>(Ab + rowA1 * 128 + ch);
            bf0[s] = *reinterpret_cast<const half8*>(Bb + colB0 * 128 + ch);
            bf1[s] = *reinterpret_cast<const half8*>(Bb + colB1 * 128 + ch);
        }
        __builtin_amdgcn_s_setprio(1);
#pragma unroll
        for (int s = 0; s < 4; ++s) {
            acc00 = __builtin_amdgcn_mfma_f32_32x32x16_f16(af0[s], bf0[s], acc00, 0, 0, 0);
            acc01 = __builtin_amdgcn_mfma_f32_32x32x16_f16(af0[s], bf1[s], acc01, 0, 0, 0);
            acc10 = __builtin_amdgcn_mfma_f32_32x32x16_f16(af1[s], bf0[s], acc10, 0, 0, 0);
            acc11 = __builtin_amdgcn_mfma_f32_32x32x16_f16(af1[s], bf1[s], acc11, 0, 0, 0);
        }
        __builtin_amdgcn_s_setprio(0);

        if (kt < 7) asm volatile("s_waitcnt vmcnt(0)" ::: "memory");
        __syncthreads();
        cur ^= 1;
    }

    const float pj0 = proj[n0 + wn * 64 + l31];
    const float pj1 = proj[n0 + wn * 64 + 32 + l31];
    float* sp = spart + (size_t)(nb * 2 + wn) * M;

#pragma unroll
    for (int reg = 0; reg < 16; ++reg) {
        float v0 = fast_tanh(acc00[reg]) * pj0 + fast_tanh(acc01[reg]) * pj1;
        float v1 = fast_tanh(acc10[reg]) * pj0 + fast_tanh(acc11[reg]) * pj1;
#pragma unroll
        for (int msk = 1; msk < 32; msk <<= 1) {
            v0 += __shfl_xor(v0, msk, 64);
            v1 += __shfl_xor(v1, msk, 64);
        }
        if (l31 == 0) {
            const int rl = (reg & 3) + 8 * (reg >> 2) + 4 * hi;
            const int m  = m0 + wm * 64 + rl;
            sp[m]      = v0;
            sp[m + 32] = v1;
        }
    }
}

// ---------- phase 2: reduce 8 partial groups + softmax over batch -> p[M]
__device__ __forceinline__ void phase_softmax(int bid, int tid,
                                              const float* __restrict__ spart,
                                              float* __restrict__ p)
{
    if (tid >= 32) return;
    const int t = bid * 4 + (tid >> 3);   // 256 blocks x 4 t = 1024
    const int b = tid & 7;
    float s = 0.f;
#pragma unroll
    for (int g2 = 0; g2 < 8; ++g2) s += spart[(size_t)g2 * M + t * 8 + b];
    float mx = s;
#pragma unroll
    for (int msk = 1; msk < 8; msk <<= 1) mx = fmaxf(mx, __shfl_xor(mx, msk, 64));
    const float e = __expf(s - mx);
    float sum = e;
#pragma unroll
    for (int msk = 1; msk < 8; msk <<= 1) sum += __shfl_xor(sum, msk, 64);
    p[t * 8 + b] = e / sum;
}

// ---------- phase 3: attend for one virtual block v (b = v&7, ig = v>>3)
__device__ __forceinline__ void phase_attend(int v, int tid,
                                             const float* __restrict__ X,
                                             const float* __restrict__ p,
                                             float* __restrict__ out)
{
    const int b    = v & 7;
    const int ig   = v >> 3;
    const int rg   = tid >> 6;
    const int lane = tid & 63;
    const int i    = ig * 4 + rg;

    const float4* X4 = reinterpret_cast<const float4*>(X);
    float4* O4       = reinterpret_cast<float4*>(out);
    const size_t obase = (size_t)(i * B + b) * (D / 4) + lane * 2;

    if (i < W) {
        O4[obase]     = X4[obase];
        O4[obase + 1] = X4[obase + 1];
        return;
    }

    float4 a0 = {0.f, 0.f, 0.f, 0.f}, a1 = {0.f, 0.f, 0.f, 0.f};
#pragma unroll 4
    for (int k = 0; k < W; ++k) {
        const int tau  = i - W + k;
        const float pw = p[tau * B + b];
        const size_t rbase = (size_t)(tau * B + b) * (D / 4) + lane * 2;
        const float4 v0 = X4[rbase];
        const float4 v1 = X4[rbase + 1];
        a0.x = fmaf(pw, v0.x, a0.x); a0.y = fmaf(pw, v0.y, a0.y);
        a0.z = fmaf(pw, v0.z, a0.z); a0.w = fmaf(pw, v0.w, a0.w);
        a1.x = fmaf(pw, v1.x, a1.x); a1.y = fmaf(pw, v1.y, a1.y);
        a1.z = fmaf(pw, v1.z, a1.z); a1.w = fmaf(pw, v1.w, a1.w);
    }
    O4[obase]     = a0;
    O4[obase + 1] = a1;
}

// ---------- single cooperative kernel ----------
__global__ __launch_bounds__(256) void fused_all(
    const float* __restrict__ X, const float* __restrict__ Wm,
    const float* __restrict__ proj, float* __restrict__ out,
    _Float16* __restrict__ Ah, _Float16* __restrict__ Bt,
    float* __restrict__ spart, float* __restrict__ p)
{
    cg::grid_group grid = cg::this_grid();
    const int bid = blockIdx.x, tid = threadIdx.x;

    phase_prep(bid, tid, X, Wm, Ah, Bt);
    __threadfence();
    grid.sync();

    phase_gemm(bid, tid, Ah, Bt, proj, spart);
    __threadfence();
    grid.sync();

    phase_softmax(bid, tid, spart, p);
    __threadfence();
    grid.sync();

    for (int v = bid; v < (T / 4) * B; v += 256)
        phase_attend(v, tid, X, p, out);
}

// ---------- non-cooperative fallback kernels ----------
__global__ __launch_bounds__(256) void k_prep(const float* X, const float* Wm,
                                              _Float16* Ah, _Float16* Bt) {
    phase_prep(blockIdx.x, threadIdx.x, X, Wm, Ah, Bt);
}
__global__ __launch_bounds__(256) void k_gemm(const _Float16* Ah, const _Float16* Bt,
                                              const float* proj, float* spart) {
    phase_gemm(blockIdx.x, threadIdx.x, Ah, Bt, proj, spart);
}
__global__ __launch_bounds__(256) void k_softmax(const float* spart, float* p) {
    phase_softmax(blockIdx.x, threadIdx.x, spart, p);
}
__global__ __launch_bounds__(256) void k_attend(const float* X, const float* p, float* out) {
    phase_attend(blockIdx.x, threadIdx.x, X, p, out);
}

extern "C" void kernel_launch(void* const* d_in, const int* in_sizes, int n_in,
                              void* d_out, int out_size, void* d_ws, size_t ws_size,
                              hipStream_t stream)
{
    const float* X    = (const float*)d_in[0];
    const float* Wm   = (const float*)d_in[1];
    const float* proj = (const float*)d_in[2];
    float* out = (float*)d_out;

    _Float16* Ah   = (_Float16*)d_ws;              // 8 MB
    _Float16* Bt   = Ah + (size_t)M * D;           // 0.5 MB
    float*    sprt = (float*)(Bt + (size_t)D * D); // 8*M floats
    float*    p    = sprt + 8 * M;                 // M floats

    void* args[8] = {(void*)&X, (void*)&Wm, (void*)&proj, (void*)&out,
                     (void*)&Ah, (void*)&Bt, (void*)&sprt, (void*)&p};
    hipError_t err = hipLaunchCooperativeKernel((void*)fused_all, dim3(256), dim3(256),
                                                args, 0, stream);
    if (err != hipSuccess) {
        (void)hipGetLastError(); // clear
        k_prep<<<256, 256, 0, stream>>>(X, Wm, Ah, Bt);
        k_gemm<<<256, 256, 0, stream>>>(Ah, Bt, proj, sprt);
        k_softmax<<<256, 256, 0, stream>>>(sprt, p);
        k_attend<<<(T / 4) * B, 256, 0, stream>>>(X, p, out);
    }
}

// Round 4
// 43.387 us; speedup vs baseline: 4.7981x; 4.7981x over previous
//
#include <hip/hip_runtime.h>
#include <cstdint>

namespace {
constexpr int T = 1024;
constexpr int B = 8;
constexpr int D = 512;
constexpr int W = 32;
constexpr int M = T * B; // 8192 rows (t*B+b)
}

using half8  = __attribute__((ext_vector_type(8))) _Float16;
using f32x16 = __attribute__((ext_vector_type(16))) float;

__device__ __forceinline__ void gload16(const void* g, void* l) {
    __builtin_amdgcn_global_load_lds(
        (const __attribute__((address_space(1))) void*)g,
        (__attribute__((address_space(3))) void*)l, 16, 0, 0);
}

__device__ __forceinline__ float fast_tanh(float x) {
    float e = __expf(2.f * x);
    return 1.f - 2.f / (e + 1.f);
}

// ---- prep (merged): X fp32 -> Ah fp16 [M][D] on all 2048 blocks;
//      W fp32 [e][d] -> Bt fp16 [d][e] via LDS transpose on blocks 0..63.
__global__ __launch_bounds__(256) void prep_merged(
    const float* __restrict__ X, const float* __restrict__ Wm,
    _Float16* __restrict__ Ah, _Float16* __restrict__ Bt)
{
    __shared__ float tile[64][65];
    const int tid = threadIdx.x;
    const int bid = blockIdx.x;

    // X conversion: one half8 chunk per thread (2048*256 == M*D/8)
    {
        const int c = bid * 256 + tid;
        const float4* X4 = reinterpret_cast<const float4*>(X);
        const float4 v0 = X4[(size_t)c * 2];
        const float4 v1 = X4[(size_t)c * 2 + 1];
        half8 h;
        h[0] = (_Float16)v0.x; h[1] = (_Float16)v0.y; h[2] = (_Float16)v0.z; h[3] = (_Float16)v0.w;
        h[4] = (_Float16)v1.x; h[5] = (_Float16)v1.y; h[6] = (_Float16)v1.z; h[7] = (_Float16)v1.w;
        *reinterpret_cast<half8*>(Ah + (size_t)c * 8) = h;
    }

    // W transpose (round-2 prep_b verbatim), blocks 0..63 only
    if (bid < 64) {
        const int bd = bid & 7;
        const int be = bid >> 3;
        const int r  = tid >> 2;
        const int c0 = (tid & 3) * 16;
        const float* src = Wm + (size_t)(be * 64 + r) * 512 + bd * 64 + c0;
#pragma unroll
        for (int j = 0; j < 16; j += 4) {
            const float4 v = *reinterpret_cast<const float4*>(src + j);
            tile[r][c0 + j]     = v.x;
            tile[r][c0 + j + 1] = v.y;
            tile[r][c0 + j + 2] = v.z;
            tile[r][c0 + j + 3] = v.w;
        }
        __syncthreads();
        const int dd = tid >> 2;
        const int e0 = (tid & 3) * 16;
        half8 h0, h1;
#pragma unroll
        for (int j = 0; j < 8; ++j)  h0[j] = (_Float16)tile[e0 + j][dd];
#pragma unroll
        for (int j = 0; j < 8; ++j)  h1[j] = (_Float16)tile[e0 + 8 + j][dd];
        _Float16* dst = Bt + (size_t)(bd * 64 + dd) * 512 + be * 64 + e0;
        *reinterpret_cast<half8*>(dst)     = h0;
        *reinterpret_cast<half8*>(dst + 8) = h1;
    }
}

// ---- fused GEMM + tanh + proj-dot -> spart[8][M] (verbatim round 2) ----
__global__ __launch_bounds__(256) void gemm_scores(
    const _Float16* __restrict__ Ah, const _Float16* __restrict__ Bt,
    const float* __restrict__ proj, float* __restrict__ spart)
{
    __shared__ char lds_buf[65536]; // [2 bufs][A 16K | B 16K]

    const int tid  = threadIdx.x;
    const int lane = tid & 63;
    const int wv   = tid >> 6;
    const int wm   = wv >> 1;
    const int wn   = wv & 1;
    const int hi   = lane >> 5;
    const int l31  = lane & 31;
    const int l7   = lane & 7;

    const int bid  = blockIdx.x;
    const int wgid = (bid & 7) * 32 + (bid >> 3); // XCD-aware swizzle
    const int mb   = wgid >> 2;
    const int nb   = wgid & 3;
    const int m0   = mb * 128;
    const int n0   = nb * 128;

    const int wbase = __builtin_amdgcn_readfirstlane(tid & ~63);

    f32x16 acc00 = {}, acc01 = {}, acc10 = {}, acc11 = {};

    auto stage = [&](int bufi, int kt) {
        char* abase = lds_buf + bufi * 32768;
        char* bbase = abase + 16384;
        const int kbase = kt * 64;
#pragma unroll
        for (int i = 0; i < 4; ++i) {
            const int c   = i * 256 + tid;
            const int row = c >> 3;
            const int ch  = c & 7;
            const int koff = kbase + ((ch ^ (row & 7)) << 3);
            gload16(Ah + (size_t)(m0 + row) * 512 + koff,
                    abase + (size_t)(i * 256 + wbase) * 16);
            gload16(Bt + (size_t)(n0 + row) * 512 + koff,
                    bbase + (size_t)(i * 256 + wbase) * 16);
        }
    };

    stage(0, 0);
    asm volatile("s_waitcnt vmcnt(0)" ::: "memory");
    __syncthreads();

    int cur = 0;
    const int rowA0 = wm * 64 + l31;
    const int rowA1 = rowA0 + 32;
    const int colB0 = wn * 64 + l31;
    const int colB1 = colB0 + 32;

    for (int kt = 0; kt < 8; ++kt) {
        if (kt < 7) stage(cur ^ 1, kt + 1);

        const char* Ab = lds_buf + cur * 32768;
        const char* Bb = Ab + 16384;

        half8 af0[4], af1[4], bf0[4], bf1[4];
#pragma unroll
        for (int s = 0; s < 4; ++s) {
            const int ch = ((2 * s + hi) ^ l7) << 4;
            af0[s] = *reinterpret_cast<const half8*>(Ab + rowA0 * 128 + ch);
            af1[s] = *reinterpret_cast<const half8*>(Ab + rowA1 * 128 + ch);
            bf0[s] = *reinterpret_cast<const half8*>(Bb + colB0 * 128 + ch);
            bf1[s] = *reinterpret_cast<const half8*>(Bb + colB1 * 128 + ch);
        }
        __builtin_amdgcn_s_setprio(1);
#pragma unroll
        for (int s = 0; s < 4; ++s) {
            acc00 = __builtin_amdgcn_mfma_f32_32x32x16_f16(af0[s], bf0[s], acc00, 0, 0, 0);
            acc01 = __builtin_amdgcn_mfma_f32_32x32x16_f16(af0[s], bf1[s], acc01, 0, 0, 0);
            acc10 = __builtin_amdgcn_mfma_f32_32x32x16_f16(af1[s], bf0[s], acc10, 0, 0, 0);
            acc11 = __builtin_amdgcn_mfma_f32_32x32x16_f16(af1[s], bf1[s], acc11, 0, 0, 0);
        }
        __builtin_amdgcn_s_setprio(0);

        if (kt < 7) asm volatile("s_waitcnt vmcnt(0)" ::: "memory");
        __syncthreads();
        cur ^= 1;
    }

    const float pj0 = proj[n0 + wn * 64 + l31];
    const float pj1 = proj[n0 + wn * 64 + 32 + l31];
    float* sp = spart + (size_t)(nb * 2 + wn) * M;

#pragma unroll
    for (int reg = 0; reg < 16; ++reg) {
        float v0 = fast_tanh(acc00[reg]) * pj0 + fast_tanh(acc01[reg]) * pj1;
        float v1 = fast_tanh(acc10[reg]) * pj0 + fast_tanh(acc11[reg]) * pj1;
#pragma unroll
        for (int msk = 1; msk < 32; msk <<= 1) {
            v0 += __shfl_xor(v0, msk, 64);
            v1 += __shfl_xor(v1, msk, 64);
        }
        if (l31 == 0) {
            const int rl = (reg & 3) + 8 * (reg >> 2) + 4 * hi;
            const int m  = m0 + wm * 64 + rl;
            sp[m]      = v0;
            sp[m + 32] = v1;
        }
    }
}

// ---- attend + in-block softmax recompute ----
// Block: b = bid&7, ig = bid>>3; wave rg handles output row i = ig*4+rg.
// For ig >= 8: rebuild p[tau, b] for tau in [4ig-32, 4ig+2] (35 values) from
// spart (L2-hot), then windowed weighted sum. ig <= 7: pure passthrough.
__global__ __launch_bounds__(256) void attend_kernel(
    const float* __restrict__ X, const float* __restrict__ spart,
    float* __restrict__ out)
{
    __shared__ float sm[35][8];
    __shared__ float p_lds[35];

    const int bid  = blockIdx.x;
    const int b    = bid & 7;
    const int ig   = bid >> 3;
    const int tid  = threadIdx.x;
    const int rg   = tid >> 6;
    const int lane = tid & 63;
    const int i    = ig * 4 + rg;

    const float4* X4 = reinterpret_cast<const float4*>(X);
    float4* O4       = reinterpret_cast<float4*>(out);
    const size_t obase = (size_t)(i * B + b) * (D / 4) + lane * 2;

    if (ig < 8) { // all four rows < W: passthrough
        O4[obase]     = X4[obase];
        O4[obase + 1] = X4[obase + 1];
        return;
    }

    const int tau0 = ig * 4 - 32;
    // step 1: raw scores s[tau, b'] = sum_g spart[g][tau*8+b'] for 35x8 entries
    for (int idx = tid; idx < 35 * 8; idx += 256) {
        const int tj = idx >> 3;
        const int bj = idx & 7;
        float s = 0.f;
#pragma unroll
        for (int g = 0; g < 8; ++g)
            s += spart[(size_t)g * M + (size_t)(tau0 + tj) * 8 + bj];
        sm[tj][bj] = s;
    }
    __syncthreads();
    // step 2: softmax over b' per tau; keep only our b
    if (tid < 35) {
        float v[8];
#pragma unroll
        for (int j = 0; j < 8; ++j) v[j] = sm[tid][j];
        float mx = v[0];
#pragma unroll
        for (int j = 1; j < 8; ++j) mx = fmaxf(mx, v[j]);
        float sum = 0.f;
#pragma unroll
        for (int j = 0; j < 8; ++j) { v[j] = __expf(v[j] - mx); sum += v[j]; }
        p_lds[tid] = v[b] / sum;
    }
    __syncthreads();

    // step 3: attend (round-2 loop, p from LDS)
    float4 a0 = {0.f, 0.f, 0.f, 0.f}, a1 = {0.f, 0.f, 0.f, 0.f};
#pragma unroll 4
    for (int k = 0; k < W; ++k) {
        const int tau  = i - W + k;
        const float pw = p_lds[rg + k];
        const size_t rbase = (size_t)(tau * B + b) * (D / 4) + lane * 2;
        const float4 v0 = X4[rbase];
        const float4 v1 = X4[rbase + 1];
        a0.x = fmaf(pw, v0.x, a0.x); a0.y = fmaf(pw, v0.y, a0.y);
        a0.z = fmaf(pw, v0.z, a0.z); a0.w = fmaf(pw, v0.w, a0.w);
        a1.x = fmaf(pw, v1.x, a1.x); a1.y = fmaf(pw, v1.y, a1.y);
        a1.z = fmaf(pw, v1.z, a1.z); a1.w = fmaf(pw, v1.w, a1.w);
    }
    O4[obase]     = a0;
    O4[obase + 1] = a1;
}

extern "C" void kernel_launch(void* const* d_in, const int* in_sizes, int n_in,
                              void* d_out, int out_size, void* d_ws, size_t ws_size,
                              hipStream_t stream)
{
    const float* X    = (const float*)d_in[0];
    const float* Wm   = (const float*)d_in[1];
    const float* proj = (const float*)d_in[2];
    float* out = (float*)d_out;

    _Float16* Ah   = (_Float16*)d_ws;              // 8 MB
    _Float16* Bt   = Ah + (size_t)M * D;           // 0.5 MB
    float*    sprt = (float*)(Bt + (size_t)D * D); // 8*M floats

    prep_merged<<<2048, 256, 0, stream>>>(X, Wm, Ah, Bt);
    gemm_scores<<<256, 256, 0, stream>>>(Ah, Bt, proj, sprt);
    attend_kernel<<<(T / 4) * B, 256, 0, stream>>>(X, sprt, out);
}

// Round 6
// 41.279 us; speedup vs baseline: 5.0431x; 1.0511x over previous
//
#include <hip/hip_runtime.h>
#include <cstdint>

namespace {
constexpr int T = 1024;
constexpr int B = 8;
constexpr int D = 512;
constexpr int W = 32;
constexpr int M = T * B; // 8192 rows (t*B+b)
}

using half8  = __attribute__((ext_vector_type(8))) _Float16;
using f32x16 = __attribute__((ext_vector_type(16))) float;

__device__ __forceinline__ void gload16(const void* g, void* l) {
    __builtin_amdgcn_global_load_lds(
        (const __attribute__((address_space(1))) void*)g,
        (__attribute__((address_space(3))) void*)l, 16, 0, 0);
}

__device__ __forceinline__ float fast_tanh(float x) {
    float e = __expf(2.f * x);
    return 1.f - 2.f / (e + 1.f);
}

// ---- prep (merged): X fp32 -> Ah fp16 [M][D] on all 2048 blocks;
//      W fp32 [e][d] -> Bt fp16 [d][e] via LDS transpose on blocks 0..63.
__global__ __launch_bounds__(256) void prep_merged(
    const float* __restrict__ X, const float* __restrict__ Wm,
    _Float16* __restrict__ Ah, _Float16* __restrict__ Bt)
{
    __shared__ float tile[64][65];
    const int tid = threadIdx.x;
    const int bid = blockIdx.x;

    // X conversion: one half8 chunk per thread (2048*256 == M*D/8)
    {
        const int c = bid * 256 + tid;
        const float4* X4 = reinterpret_cast<const float4*>(X);
        const float4 v0 = X4[(size_t)c * 2];
        const float4 v1 = X4[(size_t)c * 2 + 1];
        half8 h;
        h[0] = (_Float16)v0.x; h[1] = (_Float16)v0.y; h[2] = (_Float16)v0.z; h[3] = (_Float16)v0.w;
        h[4] = (_Float16)v1.x; h[5] = (_Float16)v1.y; h[6] = (_Float16)v1.z; h[7] = (_Float16)v1.w;
        *reinterpret_cast<half8*>(Ah + (size_t)c * 8) = h;
    }

    // W transpose, blocks 0..63 only
    if (bid < 64) {
        const int bd = bid & 7;
        const int be = bid >> 3;
        const int r  = tid >> 2;
        const int c0 = (tid & 3) * 16;
        const float* src = Wm + (size_t)(be * 64 + r) * 512 + bd * 64 + c0;
#pragma unroll
        for (int j = 0; j < 16; j += 4) {
            const float4 v = *reinterpret_cast<const float4*>(src + j);
            tile[r][c0 + j]     = v.x;
            tile[r][c0 + j + 1] = v.y;
            tile[r][c0 + j + 2] = v.z;
            tile[r][c0 + j + 3] = v.w;
        }
        __syncthreads();
        const int dd = tid >> 2;
        const int e0 = (tid & 3) * 16;
        half8 h0, h1;
#pragma unroll
        for (int j = 0; j < 8; ++j)  h0[j] = (_Float16)tile[e0 + j][dd];
#pragma unroll
        for (int j = 0; j < 8; ++j)  h1[j] = (_Float16)tile[e0 + 8 + j][dd];
        _Float16* dst = Bt + (size_t)(bd * 64 + dd) * 512 + be * 64 + e0;
        *reinterpret_cast<half8*>(dst)     = h0;
        *reinterpret_cast<half8*>(dst + 8) = h1;
    }
}

// ---- fused GEMM + tanh + proj-dot -> spart[8][M] (verbatim round 2) ----
__global__ __launch_bounds__(256) void gemm_scores(
    const _Float16* __restrict__ Ah, const _Float16* __restrict__ Bt,
    const float* __restrict__ proj, float* __restrict__ spart)
{
    __shared__ char lds_buf[65536]; // [2 bufs][A 16K | B 16K]

    const int tid  = threadIdx.x;
    const int lane = tid & 63;
    const int wv   = tid >> 6;
    const int wm   = wv >> 1;
    const int wn   = wv & 1;
    const int hi   = lane >> 5;
    const int l31  = lane & 31;
    const int l7   = lane & 7;

    const int bid  = blockIdx.x;
    const int wgid = (bid & 7) * 32 + (bid >> 3); // XCD-aware swizzle
    const int mb   = wgid >> 2;
    const int nb   = wgid & 3;
    const int m0   = mb * 128;
    const int n0   = nb * 128;

    const int wbase = __builtin_amdgcn_readfirstlane(tid & ~63);

    f32x16 acc00 = {}, acc01 = {}, acc10 = {}, acc11 = {};

    auto stage = [&](int bufi, int kt) {
        char* abase = lds_buf + bufi * 32768;
        char* bbase = abase + 16384;
        const int kbase = kt * 64;
#pragma unroll
        for (int i = 0; i < 4; ++i) {
            const int c   = i * 256 + tid;
            const int row = c >> 3;
            const int ch  = c & 7;
            const int koff = kbase + ((ch ^ (row & 7)) << 3);
            gload16(Ah + (size_t)(m0 + row) * 512 + koff,
                    abase + (size_t)(i * 256 + wbase) * 16);
            gload16(Bt + (size_t)(n0 + row) * 512 + koff,
                    bbase + (size_t)(i * 256 + wbase) * 16);
        }
    };

    stage(0, 0);
    asm volatile("s_waitcnt vmcnt(0)" ::: "memory");
    __syncthreads();

    int cur = 0;
    const int rowA0 = wm * 64 + l31;
    const int rowA1 = rowA0 + 32;
    const int colB0 = wn * 64 + l31;
    const int colB1 = colB0 + 32;

    for (int kt = 0; kt < 8; ++kt) {
        if (kt < 7) stage(cur ^ 1, kt + 1);

        const char* Ab = lds_buf + cur * 32768;
        const char* Bb = Ab + 16384;

        half8 af0[4], af1[4], bf0[4], bf1[4];
#pragma unroll
        for (int s = 0; s < 4; ++s) {
            const int ch = ((2 * s + hi) ^ l7) << 4;
            af0[s] = *reinterpret_cast<const half8*>(Ab + rowA0 * 128 + ch);
            af1[s] = *reinterpret_cast<const half8*>(Ab + rowA1 * 128 + ch);
            bf0[s] = *reinterpret_cast<const half8*>(Bb + colB0 * 128 + ch);
            bf1[s] = *reinterpret_cast<const half8*>(Bb + colB1 * 128 + ch);
        }
        __builtin_amdgcn_s_setprio(1);
#pragma unroll
        for (int s = 0; s < 4; ++s) {
            acc00 = __builtin_amdgcn_mfma_f32_32x32x16_f16(af0[s], bf0[s], acc00, 0, 0, 0);
            acc01 = __builtin_amdgcn_mfma_f32_32x32x16_f16(af0[s], bf1[s], acc01, 0, 0, 0);
            acc10 = __builtin_amdgcn_mfma_f32_32x32x16_f16(af1[s], bf0[s], acc10, 0, 0, 0);
            acc11 = __builtin_amdgcn_mfma_f32_32x32x16_f16(af1[s], bf1[s], acc11, 0, 0, 0);
        }
        __builtin_amdgcn_s_setprio(0);

        if (kt < 7) asm volatile("s_waitcnt vmcnt(0)" ::: "memory");
        __syncthreads();
        cur ^= 1;
    }

    const float pj0 = proj[n0 + wn * 64 + l31];
    const float pj1 = proj[n0 + wn * 64 + 32 + l31];
    float* sp = spart + (size_t)(nb * 2 + wn) * M;

#pragma unroll
    for (int reg = 0; reg < 16; ++reg) {
        float v0 = fast_tanh(acc00[reg]) * pj0 + fast_tanh(acc01[reg]) * pj1;
        float v1 = fast_tanh(acc10[reg]) * pj0 + fast_tanh(acc11[reg]) * pj1;
#pragma unroll
        for (int msk = 1; msk < 32; msk <<= 1) {
            v0 += __shfl_xor(v0, msk, 64);
            v1 += __shfl_xor(v1, msk, 64);
        }
        if (l31 == 0) {
            const int rl = (reg & 3) + 8 * (reg >> 2) + 4 * hi;
            const int m  = m0 + wm * 64 + rl;
            sp[m]      = v0;
            sp[m + 32] = v1;
        }
    }
}

// ---- attend v2 (fixed): block (b = bid&7, ig = bid>>3) owns outputs
// i in [32ig, 32ig+32). Stages the 63-row fp16 window [32ig-32, 32ig+31)
// into LDS once (wave-uniform LDS base for global_load_lds, per-lane global
// addr only), computes ALL 63 softmax weights with a 2-pass loop over
// 256 threads (fix for the round-5 bug: `if (tid<504)` on a 256-thread
// block left p_lds[32..62] uninitialized), then windowed weighted sum.
__global__ __launch_bounds__(256) void attend_kernel(
    const float* __restrict__ X, const _Float16* __restrict__ Ah,
    const float* __restrict__ spart, float* __restrict__ out)
{
    __shared__ _Float16 W_lds[63 * 512]; // 64512 B
    __shared__ float p_lds[64];

    const int bid = blockIdx.x;
    const int b   = bid & 7;   // b == XCD slice
    const int ig  = bid >> 3;
    const int tid = threadIdx.x;

    if (ig == 0) { // outputs 0..31: exact fp32 passthrough from X
        const float4* X4 = reinterpret_cast<const float4*>(X);
        float4* O4 = reinterpret_cast<float4*>(out);
        for (int idx = tid; idx < 32 * 128; idx += 256) {
            const int r = idx >> 7;
            const int c = idx & 127;
            const size_t off = (size_t)(r * 8 + b) * 128 + c;
            O4[off] = X4[off];
        }
        return;
    }

    const int i0   = ig * 32;
    const int tau0 = i0 - 32;
    const int lane = tid & 63;
    const int wbase = __builtin_amdgcn_readfirstlane(tid & ~63);

    // stage 63 window rows (Ah[tau0+r][b][:]) -> W_lds, 4032 x 16B chunks.
    // LDS dest is wave-uniform (cbase); global src is per-lane. Guard is
    // whole-wave uniform (4032 % 64 == 0).
    {
        const _Float16* src = Ah + (size_t)(tau0 * 8 + b) * 512;
#pragma unroll
        for (int it = 0; it < 16; ++it) {
            const int cbase = it * 256 + wbase;      // wave-uniform chunk base
            if (cbase < 4032) {
                const int c  = cbase + lane;         // per-lane chunk
                const int r  = c >> 6;               // window row (uniform in wave)
                const int ch = c & 63;               // 16B chunk in row (== lane)
                gload16(src + (size_t)r * 4096 + ch * 8,
                        (char*)W_lds + (size_t)cbase * 16);
            }
        }
    }

    // softmax weights for lt in [0, 63): 2 passes x (256 threads / 8) taus.
    const int bj = tid & 7;
#pragma unroll
    for (int half = 0; half < 2; ++half) {
        const int lt = (tid >> 3) + half * 32;
        if (lt < 63) {
            float s = 0.f;
#pragma unroll
            for (int g = 0; g < 8; ++g)
                s += spart[(size_t)g * M + (size_t)(tau0 + lt) * 8 + bj];
            float mx = s;
#pragma unroll
            for (int msk = 1; msk < 8; msk <<= 1)
                mx = fmaxf(mx, __shfl_xor(mx, msk, 64));
            const float e = __expf(s - mx);
            float sum = e;
#pragma unroll
            for (int msk = 1; msk < 8; msk <<= 1)
                sum += __shfl_xor(sum, msk, 64);
            if (bj == b) p_lds[lt] = e / sum;
        }
    }

    asm volatile("s_waitcnt vmcnt(0)" ::: "memory");
    __syncthreads();

    const int rg = tid >> 6;

#pragma unroll 2
    for (int q = 0; q < 8; ++q) {
        const int i  = i0 + rg * 8 + q;
        const int lb = rg * 8 + q;           // window local base; lt = lb + k
        float a0 = 0.f, a1 = 0.f, a2 = 0.f, a3 = 0.f;
        float a4 = 0.f, a5 = 0.f, a6 = 0.f, a7 = 0.f;
#pragma unroll 4
        for (int k = 0; k < 32; ++k) {
            const int lt = lb + k;
            const float pw = p_lds[lt];
            const half8 h = *reinterpret_cast<const half8*>(
                W_lds + (size_t)lt * 512 + lane * 8);
            a0 = fmaf(pw, (float)h[0], a0);
            a1 = fmaf(pw, (float)h[1], a1);
            a2 = fmaf(pw, (float)h[2], a2);
            a3 = fmaf(pw, (float)h[3], a3);
            a4 = fmaf(pw, (float)h[4], a4);
            a5 = fmaf(pw, (float)h[5], a5);
            a6 = fmaf(pw, (float)h[6], a6);
            a7 = fmaf(pw, (float)h[7], a7);
        }
        float4* O4 = reinterpret_cast<float4*>(
            out + (size_t)(i * 8 + b) * 512 + lane * 8);
        O4[0] = float4{a0, a1, a2, a3};
        O4[1] = float4{a4, a5, a6, a7};
    }
}

extern "C" void kernel_launch(void* const* d_in, const int* in_sizes, int n_in,
                              void* d_out, int out_size, void* d_ws, size_t ws_size,
                              hipStream_t stream)
{
    const float* X    = (const float*)d_in[0];
    const float* Wm   = (const float*)d_in[1];
    const float* proj = (const float*)d_in[2];
    float* out = (float*)d_out;

    _Float16* Ah   = (_Float16*)d_ws;              // 8 MB
    _Float16* Bt   = Ah + (size_t)M * D;           // 0.5 MB
    float*    sprt = (float*)(Bt + (size_t)D * D); // 8*M floats

    prep_merged<<<2048, 256, 0, stream>>>(X, Wm, Ah, Bt);
    gemm_scores<<<256, 256, 0, stream>>>(Ah, Bt, proj, sprt);
    attend_kernel<<<(T / W) * B, 256, 0, stream>>>(X, Ah, sprt, out);
}

// Round 7
// 41.016 us; speedup vs baseline: 5.0755x; 1.0064x over previous
//
#include <hip/hip_runtime.h>
#include <cstdint>

namespace {
constexpr int T = 1024;
constexpr int B = 8;
constexpr int D = 512;
constexpr int W = 32;
constexpr int M = T * B; // 8192 rows (t*B+b)
}

using half8  = __attribute__((ext_vector_type(8))) _Float16;
using f32x16 = __attribute__((ext_vector_type(16))) float;

__device__ __forceinline__ void gload16(const void* g, void* l) {
    __builtin_amdgcn_global_load_lds(
        (const __attribute__((address_space(1))) void*)g,
        (__attribute__((address_space(3))) void*)l, 16, 0, 0);
}

__device__ __forceinline__ float fast_tanh(float x) {
    float e = __expf(2.f * x);
    return 1.f - 2.f / (e + 1.f);
}

// ---- prep (merged): X fp32 -> Ah fp16 [M][D] on all 2048 blocks;
//      W fp32 [e][d] -> Bt fp16 [d][e] via LDS transpose on blocks 0..63.
__global__ __launch_bounds__(256) void prep_merged(
    const float* __restrict__ X, const float* __restrict__ Wm,
    _Float16* __restrict__ Ah, _Float16* __restrict__ Bt)
{
    __shared__ float tile[64][65];
    const int tid = threadIdx.x;
    const int bid = blockIdx.x;

    // X conversion: one half8 chunk per thread (2048*256 == M*D/8)
    {
        const int c = bid * 256 + tid;
        const float4* X4 = reinterpret_cast<const float4*>(X);
        const float4 v0 = X4[(size_t)c * 2];
        const float4 v1 = X4[(size_t)c * 2 + 1];
        half8 h;
        h[0] = (_Float16)v0.x; h[1] = (_Float16)v0.y; h[2] = (_Float16)v0.z; h[3] = (_Float16)v0.w;
        h[4] = (_Float16)v1.x; h[5] = (_Float16)v1.y; h[6] = (_Float16)v1.z; h[7] = (_Float16)v1.w;
        *reinterpret_cast<half8*>(Ah + (size_t)c * 8) = h;
    }

    // W transpose, blocks 0..63 only
    if (bid < 64) {
        const int bd = bid & 7;
        const int be = bid >> 3;
        const int r  = tid >> 2;
        const int c0 = (tid & 3) * 16;
        const float* src = Wm + (size_t)(be * 64 + r) * 512 + bd * 64 + c0;
#pragma unroll
        for (int j = 0; j < 16; j += 4) {
            const float4 v = *reinterpret_cast<const float4*>(src + j);
            tile[r][c0 + j]     = v.x;
            tile[r][c0 + j + 1] = v.y;
            tile[r][c0 + j + 2] = v.z;
            tile[r][c0 + j + 3] = v.w;
        }
        __syncthreads();
        const int dd = tid >> 2;
        const int e0 = (tid & 3) * 16;
        half8 h0, h1;
#pragma unroll
        for (int j = 0; j < 8; ++j)  h0[j] = (_Float16)tile[e0 + j][dd];
#pragma unroll
        for (int j = 0; j < 8; ++j)  h1[j] = (_Float16)tile[e0 + 8 + j][dd];
        _Float16* dst = Bt + (size_t)(bd * 64 + dd) * 512 + be * 64 + e0;
        *reinterpret_cast<half8*>(dst)     = h0;
        *reinterpret_cast<half8*>(dst + 8) = h1;
    }
}

// ---- fused GEMM + tanh + proj-dot -> spart[8][M] ----
// v2: tile 64M x 128N, grid 512 blocks (2/CU co-resident -> the per-kt
// vmcnt(0)+barrier drain of one block hides under the other block's
// MFMA/ds_read: round-6 ran 1 block/CU and was ~60% barrier-drain stall).
// 4 waves, each 32x64 (acc 2x f32x16 = 32 AGPR). LDS 2 bufs x (A 8K + B 16K)
// = 48 KB. Same XOR-swizzled staging/fragment pattern as the proven round-2
// kernel; identical K-accumulation order (bitwise-same results).
__global__ __launch_bounds__(256) void gemm_scores(
    const _Float16* __restrict__ Ah, const _Float16* __restrict__ Bt,
    const float* __restrict__ proj, float* __restrict__ spart)
{
    __shared__ char lds_buf[49152]; // [2 bufs][A 8K | B 16K]

    const int tid  = threadIdx.x;
    const int lane = tid & 63;
    const int wv   = tid >> 6;
    const int wm   = wv >> 1;       // 0..1: row half (32 rows each)
    const int wn   = wv & 1;        // 0..1: col half (64 cols each)
    const int hi   = lane >> 5;
    const int l31  = lane & 31;
    const int l7   = lane & 7;

    const int bid  = blockIdx.x;
    const int wgid = (bid & 7) * 64 + (bid >> 3); // XCD-aware swizzle (512 = 8*64)
    const int mb   = wgid >> 2;     // 0..127
    const int nb   = wgid & 3;      // 0..3
    const int m0   = mb * 64;
    const int n0   = nb * 128;

    const int wbase = __builtin_amdgcn_readfirstlane(tid & ~63);

    f32x16 acc0 = {}, acc1 = {};

    auto stage = [&](int bufi, int kt) {
        char* abase = lds_buf + bufi * 24576;
        char* bbase = abase + 8192;
        const int kbase = kt * 64;
        // A: 64 rows x 8 chunks = 512 chunks
#pragma unroll
        for (int i = 0; i < 2; ++i) {
            const int c   = i * 256 + tid;
            const int row = c >> 3;
            const int ch  = c & 7;
            const int koff = kbase + ((ch ^ (row & 7)) << 3);
            gload16(Ah + (size_t)(m0 + row) * 512 + koff,
                    abase + (size_t)(i * 256 + wbase) * 16);
        }
        // B: 128 rows x 8 chunks = 1024 chunks
#pragma unroll
        for (int i = 0; i < 4; ++i) {
            const int c   = i * 256 + tid;
            const int row = c >> 3;
            const int ch  = c & 7;
            const int koff = kbase + ((ch ^ (row & 7)) << 3);
            gload16(Bt + (size_t)(n0 + row) * 512 + koff,
                    bbase + (size_t)(i * 256 + wbase) * 16);
        }
    };

    stage(0, 0);
    asm volatile("s_waitcnt vmcnt(0)" ::: "memory");
    __syncthreads();

    int cur = 0;
    const int rowA  = wm * 32 + l31;        // rowA & 7 == l7
    const int colB0 = wn * 64 + l31;
    const int colB1 = colB0 + 32;

    for (int kt = 0; kt < 8; ++kt) {
        if (kt < 7) stage(cur ^ 1, kt + 1);

        const char* Ab = lds_buf + cur * 24576;
        const char* Bb = Ab + 8192;

        half8 af[4], bf0[4], bf1[4];
#pragma unroll
        for (int s = 0; s < 4; ++s) {
            const int ch = ((2 * s + hi) ^ l7) << 4;
            af[s]  = *reinterpret_cast<const half8*>(Ab + rowA  * 128 + ch);
            bf0[s] = *reinterpret_cast<const half8*>(Bb + colB0 * 128 + ch);
            bf1[s] = *reinterpret_cast<const half8*>(Bb + colB1 * 128 + ch);
        }
        __builtin_amdgcn_s_setprio(1);
#pragma unroll
        for (int s = 0; s < 4; ++s) {
            acc0 = __builtin_amdgcn_mfma_f32_32x32x16_f16(af[s], bf0[s], acc0, 0, 0, 0);
            acc1 = __builtin_amdgcn_mfma_f32_32x32x16_f16(af[s], bf1[s], acc1, 0, 0, 0);
        }
        __builtin_amdgcn_s_setprio(0);

        if (kt < 7) asm volatile("s_waitcnt vmcnt(0)" ::: "memory");
        __syncthreads();
        cur ^= 1;
    }

    // Epilogue: per-wave 64-col partial of sum tanh(c)*proj over its 32 rows.
    const float pj0 = proj[n0 + wn * 64 + l31];
    const float pj1 = proj[n0 + wn * 64 + 32 + l31];
    float* sp = spart + (size_t)(nb * 2 + wn) * M;

#pragma unroll
    for (int reg = 0; reg < 16; ++reg) {
        float v0 = fast_tanh(acc0[reg]) * pj0 + fast_tanh(acc1[reg]) * pj1;
#pragma unroll
        for (int msk = 1; msk < 32; msk <<= 1)
            v0 += __shfl_xor(v0, msk, 64);
        if (l31 == 0) {
            const int rl = (reg & 3) + 8 * (reg >> 2) + 4 * hi;
            sp[m0 + wm * 32 + rl] = v0;
        }
    }
}

// ---- attend (round-6 verbatim, known-good) ----
__global__ __launch_bounds__(256) void attend_kernel(
    const float* __restrict__ X, const _Float16* __restrict__ Ah,
    const float* __restrict__ spart, float* __restrict__ out)
{
    __shared__ _Float16 W_lds[63 * 512]; // 64512 B
    __shared__ float p_lds[64];

    const int bid = blockIdx.x;
    const int b   = bid & 7;   // b == XCD slice
    const int ig  = bid >> 3;
    const int tid = threadIdx.x;

    if (ig == 0) { // outputs 0..31: exact fp32 passthrough from X
        const float4* X4 = reinterpret_cast<const float4*>(X);
        float4* O4 = reinterpret_cast<float4*>(out);
        for (int idx = tid; idx < 32 * 128; idx += 256) {
            const int r = idx >> 7;
            const int c = idx & 127;
            const size_t off = (size_t)(r * 8 + b) * 128 + c;
            O4[off] = X4[off];
        }
        return;
    }

    const int i0   = ig * 32;
    const int tau0 = i0 - 32;
    const int lane = tid & 63;
    const int wbase = __builtin_amdgcn_readfirstlane(tid & ~63);

    // stage 63 window rows (Ah[tau0+r][b][:]) -> W_lds, 4032 x 16B chunks.
    {
        const _Float16* src = Ah + (size_t)(tau0 * 8 + b) * 512;
#pragma unroll
        for (int it = 0; it < 16; ++it) {
            const int cbase = it * 256 + wbase;      // wave-uniform chunk base
            if (cbase < 4032) {
                const int c  = cbase + lane;         // per-lane chunk
                const int r  = c >> 6;               // window row
                const int ch = c & 63;               // 16B chunk in row
                gload16(src + (size_t)r * 4096 + ch * 8,
                        (char*)W_lds + (size_t)cbase * 16);
            }
        }
    }

    // softmax weights for lt in [0, 63): 2 passes x 32 taus.
    const int bj = tid & 7;
#pragma unroll
    for (int half = 0; half < 2; ++half) {
        const int lt = (tid >> 3) + half * 32;
        if (lt < 63) {
            float s = 0.f;
#pragma unroll
            for (int g = 0; g < 8; ++g)
                s += spart[(size_t)g * M + (size_t)(tau0 + lt) * 8 + bj];
            float mx = s;
#pragma unroll
            for (int msk = 1; msk < 8; msk <<= 1)
                mx = fmaxf(mx, __shfl_xor(mx, msk, 64));
            const float e = __expf(s - mx);
            float sum = e;
#pragma unroll
            for (int msk = 1; msk < 8; msk <<= 1)
                sum += __shfl_xor(sum, msk, 64);
            if (bj == b) p_lds[lt] = e / sum;
        }
    }

    asm volatile("s_waitcnt vmcnt(0)" ::: "memory");
    __syncthreads();

    const int rg = tid >> 6;

#pragma unroll 2
    for (int q = 0; q < 8; ++q) {
        const int i  = i0 + rg * 8 + q;
        const int lb = rg * 8 + q;           // window local base; lt = lb + k
        float a0 = 0.f, a1 = 0.f, a2 = 0.f, a3 = 0.f;
        float a4 = 0.f, a5 = 0.f, a6 = 0.f, a7 = 0.f;
#pragma unroll 4
        for (int k = 0; k < 32; ++k) {
            const int lt = lb + k;
            const float pw = p_lds[lt];
            const half8 h = *reinterpret_cast<const half8*>(
                W_lds + (size_t)lt * 512 + lane * 8);
            a0 = fmaf(pw, (float)h[0], a0);
            a1 = fmaf(pw, (float)h[1], a1);
            a2 = fmaf(pw, (float)h[2], a2);
            a3 = fmaf(pw, (float)h[3], a3);
            a4 = fmaf(pw, (float)h[4], a4);
            a5 = fmaf(pw, (float)h[5], a5);
            a6 = fmaf(pw, (float)h[6], a6);
            a7 = fmaf(pw, (float)h[7], a7);
        }
        float4* O4 = reinterpret_cast<float4*>(
            out + (size_t)(i * 8 + b) * 512 + lane * 8);
        O4[0] = float4{a0, a1, a2, a3};
        O4[1] = float4{a4, a5, a6, a7};
    }
}

extern "C" void kernel_launch(void* const* d_in, const int* in_sizes, int n_in,
                              void* d_out, int out_size, void* d_ws, size_t ws_size,
                              hipStream_t stream)
{
    const float* X    = (const float*)d_in[0];
    const float* Wm   = (const float*)d_in[1];
    const float* proj = (const float*)d_in[2];
    float* out = (float*)d_out;

    _Float16* Ah   = (_Float16*)d_ws;              // 8 MB
    _Float16* Bt   = Ah + (size_t)M * D;           // 0.5 MB
    float*    sprt = (float*)(Bt + (size_t)D * D); // 8*M floats

    prep_merged<<<2048, 256, 0, stream>>>(X, Wm, Ah, Bt);
    gemm_scores<<<512, 256, 0, stream>>>(Ah, Bt, proj, sprt);
    attend_kernel<<<(T / W) * B, 256, 0, stream>>>(X, Ah, sprt, out);
}